// Round 1
// baseline (771.382 us; speedup 1.0000x reference)
//
#include <hip/hip_runtime.h>
#include <hip/hip_bf16.h>

// ---------------------------------------------------------------------------
// DenseCorr2d_full — two-pass fp32 baseline.
//
// Stage 1 (corr_kernel):
//   corr[b, cm*16+ct, y, x] = sum_{i,j<16} tm_pad[b,cm,y+i,x+j] * tp[b,ct,i,j]
//   tm_pad = edge-replication pad bottom/right only (clamp index to 127).
//   Materialized into d_ws, chunked over cm (S chunks) if ws_size is small.
//
// Stage 2 (merge_kernel):
//   out[b,co,y,x] = bias[co] + sum_{c,ky,kx} corr[b,c,y+ky-1,x+kx-1]*W[co,c,ky,kx]
//   (3x3 SAME conv, zero pad). Accumulates across cm-chunks into d_out.
//
// Both kernels are register-tiled so the DS-instruction count per FMA keeps the
// LDS pipe at/below the VALU floor (see session notes: per-CU DS cyc ~= FMA cyc).
// ---------------------------------------------------------------------------

__global__ __launch_bounds__(256) void corr_kernel(
    const float* __restrict__ tp, const float* __restrict__ tm,
    float* __restrict__ corr, int cm0, int CmC)
{
    // sm_tm stride 84 (not 80): keeps b128 row loads spread over 8 start banks.
    __shared__ float sm_tm[47 * 84];   // 15792 B
    __shared__ float sm_tp[256 * 8];   //  8192 B  [ij][ctl], float4-readable over ct

    const int t   = threadIdx.x;
    const int x0  = (blockIdx.x & 1) << 6;   // 0,64
    const int y0  = (blockIdx.x >> 1) << 5;  // 0,32,64,96
    const int cl  = (int)blockIdx.y % CmC;
    const int b   = (int)blockIdx.y / CmC;
    const int cm  = cm0 + cl;
    const int ct0 = (int)blockIdx.z << 3;    // 0 or 8

    // Stage tomatch region [y0..y0+46][x0..x0+83] with edge clamp (min(.,127)).
    const float* tm_base = tm + (((size_t)(b * 16 + cm)) << 14);
    for (int e = t; e < 47 * 84; e += 256) {
        int r = e / 84, c = e - r * 84;
        int gy = y0 + r; gy = gy > 127 ? 127 : gy;
        int gx = x0 + c; gx = gx > 127 ? 127 : gx;
        sm_tm[e] = tm_base[(gy << 7) + gx];
    }
    // Stage template half: sm_tp[ij*8 + ctl] = tp[b][ct0+ctl][ij]
    const float* tp_base = tp + (((size_t)(b * 16 + ct0)) << 8);
    for (int e = t; e < 2048; e += 256) {
        int ij = e >> 3, ctl = e & 7;
        sm_tp[e] = tp_base[(ctl << 8) + ij];
    }
    __syncthreads();

    const int ty  = t >> 3;          // 0..31
    const int txg = (t & 7) << 3;    // 0,8,..,56  (8 positions per thread)

    float acc[8][8];                 // [ct][pos]
#pragma unroll
    for (int c = 0; c < 8; ++c)
#pragma unroll
        for (int p = 0; p < 8; ++p) acc[c][p] = 0.f;

    const float* tmrow = sm_tm + ty * 84 + txg;
#pragma unroll 1
    for (int i = 0; i < 16; ++i) {
        // Row buffer: 24 floats (need 23: 8 pos + 15 j-slide) via 6 b128 reads.
        float r[24];
        const float4* rp = (const float4*)(tmrow + i * 84);
#pragma unroll
        for (int q = 0; q < 6; ++q) {
            float4 v = rp[q];
            r[4*q] = v.x; r[4*q+1] = v.y; r[4*q+2] = v.z; r[4*q+3] = v.w;
        }
#pragma unroll
        for (int j = 0; j < 16; ++j) {
            const float4* w4 = (const float4*)(sm_tp + (((i << 4) + j) << 3));
            float4 wa = w4[0], wb = w4[1];   // broadcast reads (uniform addr)
            float wv[8] = {wa.x, wa.y, wa.z, wa.w, wb.x, wb.y, wb.z, wb.w};
#pragma unroll
            for (int c = 0; c < 8; ++c)
#pragma unroll
                for (int p = 0; p < 8; ++p)
                    acc[c][p] += r[j + p] * wv[c];
        }
    }

    const int oy = y0 + ty, ox = x0 + txg;
#pragma unroll
    for (int c = 0; c < 8; ++c) {
        float* op = corr + (((((size_t)(b * CmC + cl)) << 4) + ct0 + c) << 14)
                         + (oy << 7) + ox;
        ((float4*)op)[0] = make_float4(acc[c][0], acc[c][1], acc[c][2], acc[c][3]);
        ((float4*)op)[1] = make_float4(acc[c][4], acc[c][5], acc[c][6], acc[c][7]);
    }
}

__global__ __launch_bounds__(256) void merge_kernel(
    const float* __restrict__ corr, const float* __restrict__ Wt,
    const float* __restrict__ bias, float* __restrict__ out,
    int c0, int NCloc, int first)
{
    __shared__ float sm_c[8 * 6 * 68];   // [ch][row(6)][col stride 68] = 13056 B
    __shared__ float sm_w[72 * 76];      // [g = c*9+k][co stride 76]   = 21888 B

    const int t   = threadIdx.x;
    const int x0  = (int)blockIdx.x << 6;   // 0,64
    const int y0  = (int)blockIdx.y << 2;   // 0..124
    const int b   = (int)blockIdx.z;
    const int co0 = (t >> 5) << 3;          // 8 couts per thread
    const int s   = t & 31;
    const int px8 = (s & 7) << 3;           // 8 positions along x per thread
    const int pyl = s >> 3;                 // 0..3

    float acc[8][8];                        // [co][pos]
#pragma unroll
    for (int c = 0; c < 8; ++c)
#pragma unroll
        for (int p = 0; p < 8; ++p) acc[c][p] = 0.f;

    const float* corr_b = corr + ((size_t)b * NCloc << 14);
    const int wbase = c0 * 9;

#pragma unroll 1
    for (int cb = 0; cb < NCloc; cb += 8) {
        // Stage corr halo tile: 8 ch x 6 rows x 66 cols (col 0 <-> gx = x0-1), zero-fill OOB.
        for (int e = t; e < 8 * 6 * 66; e += 256) {
            int ch  = e / 396;
            int rem = e - ch * 396;
            int row = rem / 66;
            int col = rem - row * 66;
            int gy = y0 - 1 + row;
            int gx = x0 - 1 + col;
            float v = 0.f;
            if ((unsigned)gy < 128u && (unsigned)gx < 128u)
                v = corr_b[(((size_t)(cb + ch)) << 14) + (gy << 7) + gx];
            sm_c[ch * 408 + row * 68 + col] = v;
        }
        // Stage W slice: coalesced global (g fastest), LDS layout [g][co].
        for (int e = t; e < 64 * 72; e += 256) {
            int co = e / 72;
            int g  = e - co * 72;           // g = c*9 + ky*3 + kx
            sm_w[g * 76 + co] = Wt[(size_t)co * 2304 + wbase + cb * 9 + g];
        }
        __syncthreads();

#pragma unroll 1
        for (int c = 0; c < 8; ++c) {
#pragma unroll
            for (int ky = 0; ky < 3; ++ky) {
                float r[12];                // need r[0..9]
                const float4* rp = (const float4*)(sm_c + c * 408 + (pyl + ky) * 68 + px8);
#pragma unroll
                for (int q = 0; q < 3; ++q) {
                    float4 v = rp[q];
                    r[4*q] = v.x; r[4*q+1] = v.y; r[4*q+2] = v.z; r[4*q+3] = v.w;
                }
#pragma unroll
                for (int kx = 0; kx < 3; ++kx) {
                    const float* wr = sm_w + (c * 9 + ky * 3 + kx) * 76 + co0;
                    float4 wa = *(const float4*)wr;
                    float4 wb = *(const float4*)(wr + 4);
                    float wv[8] = {wa.x, wa.y, wa.z, wa.w, wb.x, wb.y, wb.z, wb.w};
#pragma unroll
                    for (int co = 0; co < 8; ++co)
#pragma unroll
                        for (int p = 0; p < 8; ++p)
                            acc[co][p] += r[kx + p] * wv[co];
                }
            }
        }
        __syncthreads();
    }

    const int oy = y0 + pyl;
    const int ox = x0 + px8;
#pragma unroll
    for (int co = 0; co < 8; ++co) {
        float* op = out + (((size_t)((b << 6) + co0 + co)) << 14) + (oy << 7) + ox;
        float4 v0 = make_float4(acc[co][0], acc[co][1], acc[co][2], acc[co][3]);
        float4 v1 = make_float4(acc[co][4], acc[co][5], acc[co][6], acc[co][7]);
        if (first) {
            float bv = bias[co0 + co];
            v0.x += bv; v0.y += bv; v0.z += bv; v0.w += bv;
            v1.x += bv; v1.y += bv; v1.z += bv; v1.w += bv;
        } else {
            float4 o0 = ((const float4*)op)[0];
            float4 o1 = ((const float4*)op)[1];
            v0.x += o0.x; v0.y += o0.y; v0.z += o0.z; v0.w += o0.w;
            v1.x += o1.x; v1.y += o1.y; v1.z += o1.z; v1.w += o1.w;
        }
        ((float4*)op)[0] = v0;
        ((float4*)op)[1] = v1;
    }
}

extern "C" void kernel_launch(void* const* d_in, const int* in_sizes, int n_in,
                              void* d_out, int out_size, void* d_ws, size_t ws_size,
                              hipStream_t stream)
{
    const float* tp   = (const float*)d_in[0];   // template [8,16,16,16]
    const float* tm   = (const float*)d_in[1];   // tomatch  [8,16,128,128]
    const float* Wt   = (const float*)d_in[2];   // W        [64,256,3,3]
    const float* bias = (const float*)d_in[3];   // b        [64]
    float* out  = (float*)d_out;                 // [8,64,128,128] fp32
    float* corr = (float*)d_ws;

    // corr full size = 8*256*128*128*4 = 134217728 B. Chunk Cm into S pieces so
    // the per-chunk corr fits ws_size. S is a pure function of ws_size ->
    // identical launch sequence every call (graph-capture safe).
    const size_t full = (size_t)8 * 256 * 128 * 128 * 4;
    int S = 1;
    while (S < 16 && full / (size_t)S > ws_size) S <<= 1;
    const int CmC   = 16 / S;      // cm channels per chunk
    const int NCloc = CmC * 16;    // corr channels per chunk

    for (int sc = 0; sc < S; ++sc) {
        const int cm0 = sc * CmC;
        dim3 g1(8, 8 * CmC, 2);    // tiles x (b*CmC) x ct-halves
        corr_kernel<<<g1, dim3(256), 0, stream>>>(tp, tm, corr, cm0, CmC);
        dim3 g2(2, 32, 8);         // x-tiles x y-tiles x b
        merge_kernel<<<g2, dim3(256), 0, stream>>>(corr, Wt, bias, out,
                                                   cm0 * 16, NCloc, sc == 0 ? 1 : 0);
    }
}

// Round 2
// 333.910 us; speedup vs baseline: 2.3102x; 2.3102x over previous
//
#include <hip/hip_runtime.h>
#include <hip/hip_bf16.h>

// ---------------------------------------------------------------------------
// DenseCorr2d_full — corr in fp32 VALU (writes bf16 NHWC), merge on MFMA bf16.
//
// ws layout per chunk: corrb bf16 NHWC [8][128][128][NCloc]  then
//                      Wb    bf16      [9][64][NCpad]        (zero-padded K)
// ---------------------------------------------------------------------------

typedef __attribute__((ext_vector_type(4))) float  f32x4;
typedef __attribute__((ext_vector_type(8))) short  bf16x8;

__device__ inline unsigned int pack_bf16x2(float a, float b) {
    unsigned int ua = __builtin_bit_cast(unsigned int, a);
    unsigned int ub = __builtin_bit_cast(unsigned int, b);
    ua = (ua + 0x7fffu + ((ua >> 16) & 1u)) >> 16;   // RNE
    ub = (ub + 0x7fffu + ((ub >> 16) & 1u)) >> 16;
    return ua | (ub << 16);
}

// ---------------- Stage 1: dense correlation (fp32 compute, bf16 NHWC out) --
__global__ __launch_bounds__(256) void corr_kernel(
    const float* __restrict__ tp, const float* __restrict__ tm,
    unsigned short* __restrict__ corrb, int cm0, int CmC)
{
    __shared__ float sm_tm[47 * 84];
    __shared__ float sm_tp[256 * 8];

    const int t   = threadIdx.x;
    const int x0  = (blockIdx.x & 1) << 6;
    const int y0  = (blockIdx.x >> 1) << 5;
    const int cl  = (int)blockIdx.y % CmC;
    const int b   = (int)blockIdx.y / CmC;
    const int cm  = cm0 + cl;
    const int ct0 = (int)blockIdx.z << 3;
    const int NCloc = CmC << 4;

    const float* tm_base = tm + (((size_t)(b * 16 + cm)) << 14);
    for (int e = t; e < 47 * 84; e += 256) {
        int r = e / 84, c = e - r * 84;
        int gy = y0 + r; gy = gy > 127 ? 127 : gy;   // edge-replication pad
        int gx = x0 + c; gx = gx > 127 ? 127 : gx;
        sm_tm[e] = tm_base[(gy << 7) + gx];
    }
    const float* tp_base = tp + (((size_t)(b * 16 + ct0)) << 8);
    for (int e = t; e < 2048; e += 256) {
        int ij = e >> 3, ctl = e & 7;
        sm_tp[e] = tp_base[(ctl << 8) + ij];
    }
    __syncthreads();

    const int ty  = t >> 3;
    const int txg = (t & 7) << 3;

    float acc[8][8];
#pragma unroll
    for (int c = 0; c < 8; ++c)
#pragma unroll
        for (int p = 0; p < 8; ++p) acc[c][p] = 0.f;

    const float* tmrow = sm_tm + ty * 84 + txg;
#pragma unroll 1
    for (int i = 0; i < 16; ++i) {
        float r[24];
        const float4* rp = (const float4*)(tmrow + i * 84);
#pragma unroll
        for (int q = 0; q < 6; ++q) {
            float4 v = rp[q];
            r[4*q] = v.x; r[4*q+1] = v.y; r[4*q+2] = v.z; r[4*q+3] = v.w;
        }
#pragma unroll
        for (int j = 0; j < 16; ++j) {
            const float4* w4 = (const float4*)(sm_tp + (((i << 4) + j) << 3));
            float4 wa = w4[0], wb = w4[1];
            float wv[8] = {wa.x, wa.y, wa.z, wa.w, wb.x, wb.y, wb.z, wb.w};
#pragma unroll
            for (int c = 0; c < 8; ++c)
#pragma unroll
                for (int p = 0; p < 8; ++p)
                    acc[c][p] += r[j + p] * wv[c];
        }
    }

    // Epilogue: bf16 NHWC [b][y][x][cl*16+ct0+c]
    const int oy = y0 + ty, ox = x0 + txg;
    const size_t posbase = (size_t)b * 16384 + (oy << 7) + ox;
#pragma unroll
    for (int p = 0; p < 8; ++p) {
        uint4 v;
        v.x = pack_bf16x2(acc[0][p], acc[1][p]);
        v.y = pack_bf16x2(acc[2][p], acc[3][p]);
        v.z = pack_bf16x2(acc[4][p], acc[5][p]);
        v.w = pack_bf16x2(acc[6][p], acc[7][p]);
        *(uint4*)(corrb + (posbase + p) * NCloc + (cl << 4) + ct0) = v;
    }
}

// ---------------- W transform: [co][cin][3][3] fp32 -> Wb[kk][co][cpad] bf16 -
__global__ __launch_bounds__(256) void wt_kernel(
    const float* __restrict__ W, unsigned short* __restrict__ Wb,
    int c0g, int NCloc, int NCpad)
{
    int idx = (int)blockIdx.x * 256 + (int)threadIdx.x;
    int total = 9 * 64 * NCpad;
    if (idx >= total) return;
    int cloc = idx % NCpad;
    int rem  = idx / NCpad;
    int co   = rem % 64;
    int kk   = rem / 64;
    float v = 0.f;
    if (cloc < NCloc) v = W[(size_t)co * 2304 + (size_t)(c0g + cloc) * 9 + kk];
    unsigned int u = __builtin_bit_cast(unsigned int, v);
    Wb[idx] = (unsigned short)((u + 0x7fffu + ((u >> 16) & 1u)) >> 16);
}

// ---------------- Stage 2: 3x3 SAME merge conv on MFMA bf16 -----------------
// Block: 256 thr = 4 waves; tile 64co x (8y x 32x). Wave w: rows {2w,2w+1}.
// LDS patch: [10 rows][34 cols][64 c] bf16, col stride 72 shorts (144 B) ->
// bank-verified conflict-free for both staging b128 writes and B-frag reads.
__global__ __launch_bounds__(256) void merge_mfma(
    const unsigned short* __restrict__ corrb, const unsigned short* __restrict__ Wb,
    const float* __restrict__ bias, float* __restrict__ out,
    int NCloc, int NCpad, int first)
{
    __shared__ __align__(16) unsigned short sm[10 * 34 * 72];  // 48960 B

    const int t    = threadIdx.x;
    const int wave = t >> 6;
    const int lane = t & 63;
    const int n    = lane & 15;         // MFMA col (position / B n-index)
    const int quad = lane >> 4;         // MFMA k-block / D row-block
    const int x0   = (int)blockIdx.x << 5;   // 0,32,64,96
    const int y0   = (int)blockIdx.y << 3;   // 0..120
    const int b    = (int)blockIdx.z;

    f32x4 acc[4][4];                    // [co-tile][n-tile]
#pragma unroll
    for (int a = 0; a < 4; ++a)
#pragma unroll
        for (int q = 0; q < 4; ++q) acc[a][q] = (f32x4){0.f, 0.f, 0.f, 0.f};

    const unsigned short* cb = corrb + (size_t)b * 16384 * NCloc;

#pragma unroll 1
    for (int c0 = 0; c0 < NCpad; c0 += 64) {
        __syncthreads();
        // stage halo patch: 10 x 34 positions x 64 channels (16B chunks)
        for (int e = t; e < 2720; e += 256) {
            int ci  = e & 7;
            int rem = e >> 3;
            int cc  = rem % 34;
            int r   = rem / 34;
            int gy = y0 - 1 + r;
            int gx = x0 - 1 + cc;
            int c  = c0 + (ci << 3);
            uint4 v = {0u, 0u, 0u, 0u};
            if ((unsigned)gy < 128u && (unsigned)gx < 128u && c < NCloc)
                v = *(const uint4*)(cb + ((size_t)((gy << 7) + gx)) * NCloc + c);
            *(uint4*)&sm[r * 2448 + cc * 72 + (ci << 3)] = v;
        }
        __syncthreads();

#pragma unroll 1
        for (int kk = 0; kk < 9; ++kk) {
            const int dy = kk / 3, dx = kk - 3 * (kk / 3);
#pragma unroll
            for (int kc = 0; kc < 2; ++kc) {
                // A-frags: Wb[kk][co=ct*16+n][c0+kc*32+quad*8 ..+7]
                bf16x8 af[4];
                const unsigned short* wp =
                    Wb + (size_t)kk * 64 * NCpad + (size_t)n * NCpad
                       + c0 + (kc << 5) + (quad << 3);
#pragma unroll
                for (int ct = 0; ct < 4; ++ct)
                    af[ct] = *(const bf16x8*)(wp + (size_t)(ct << 4) * NCpad);
#pragma unroll
                for (int nt = 0; nt < 4; ++nt) {
                    const int prow = 2 * wave + (nt >> 1) + dy;      // 0..9
                    const int pcol = ((nt & 1) << 4) + n + dx;       // 0..33
                    bf16x8 bf = *(const bf16x8*)&sm[prow * 2448 + pcol * 72
                                                    + (kc << 5) + (quad << 3)];
#pragma unroll
                    for (int ct = 0; ct < 4; ++ct)
                        acc[ct][nt] = __builtin_amdgcn_mfma_f32_16x16x32_bf16(
                            af[ct], bf, acc[ct][nt], 0, 0, 0);
                }
            }
        }
    }

    // Epilogue: D[row=quad*4+reg][col=n] -> out[b][co][y][x], accumulate chunks
#pragma unroll
    for (int ct = 0; ct < 4; ++ct) {
#pragma unroll
        for (int nt = 0; nt < 4; ++nt) {
            const int y   = y0 + 2 * wave + (nt >> 1);
            const int x   = x0 + ((nt & 1) << 4) + n;
            const int co0 = (ct << 4) + (quad << 2);
            float* op = out + (((size_t)((b << 6) + co0) << 7) + y) * 128 + x;
#pragma unroll
            for (int r = 0; r < 4; ++r) {
                float v = acc[ct][nt][r];
                float* pp = op + ((size_t)r << 14);
                if (first) v += bias[co0 + r];
                else       v += *pp;
                *pp = v;
            }
        }
    }
}

extern "C" void kernel_launch(void* const* d_in, const int* in_sizes, int n_in,
                              void* d_out, int out_size, void* d_ws, size_t ws_size,
                              hipStream_t stream)
{
    const float* tp   = (const float*)d_in[0];   // template [8,16,16,16]
    const float* tm   = (const float*)d_in[1];   // tomatch  [8,16,128,128]
    const float* Wt   = (const float*)d_in[2];   // W        [64,256,3,3]
    const float* bias = (const float*)d_in[3];   // b        [64]
    float* out = (float*)d_out;                  // [8,64,128,128] fp32

    // Chunk Cm into S pieces so (bf16 corr chunk + Wb slice) fits ws_size.
    int S = 1;
    for (;;) {
        int NCloc = 256 / S;
        int NCpad = (NCloc + 63) & ~63;
        size_t need = (size_t)8 * 16384 * NCloc * 2 + (size_t)9 * 64 * NCpad * 2 + 512;
        if (need <= ws_size || S == 16) break;
        S <<= 1;
    }
    const int CmC   = 16 / S;
    const int NCloc = CmC << 4;
    const int NCpad = (NCloc + 63) & ~63;

    unsigned short* corrb = (unsigned short*)d_ws;
    unsigned short* Wb    = corrb + (size_t)8 * 16384 * NCloc;

    for (int sc = 0; sc < S; ++sc) {
        dim3 g1(8, 8 * CmC, 2);
        corr_kernel<<<g1, dim3(256), 0, stream>>>(tp, tm, corrb, sc * CmC, CmC);
        int wtotal = 9 * 64 * NCpad;
        wt_kernel<<<dim3((wtotal + 255) / 256), dim3(256), 0, stream>>>(
            Wt, Wb, sc * NCloc, NCloc, NCpad);
        dim3 g2(4, 16, 8);
        merge_mfma<<<g2, dim3(256), 0, stream>>>(corrb, Wb, bias, out,
                                                 NCloc, NCpad, sc == 0 ? 1 : 0);
    }
}

// Round 3
// 207.244 us; speedup vs baseline: 3.7221x; 1.6112x over previous
//
#include <hip/hip_runtime.h>
#include <hip/hip_bf16.h>

// ---------------------------------------------------------------------------
// DenseCorr2d_full — corr AND merge on MFMA bf16.
//
// corr_mfma: per (b, cm-pair, 16-row y-tile): C[m=16 y][n=16 ct], K=256=(i,j).
//   A = tm sliding patches from LDS (two parity-shifted copies -> all reads
//   dword-aligned ds_read2_b32). B = templates, register-cached (32 VGPR).
//   Epilogue: per-wave LDS transpose -> full 64-B-line NHWC bf16 stores.
// merge_mfma: unchanged from round 2 (known good).
// ws layout: corrb bf16 NHWC [8][128][128][256], then Wb bf16 [9][64][256].
// ---------------------------------------------------------------------------

typedef __attribute__((ext_vector_type(4))) float  f32x4;
typedef __attribute__((ext_vector_type(8))) short  bf16x8;

__device__ inline unsigned int pack_bf16x2(float a, float b) {
    unsigned int ua = __builtin_bit_cast(unsigned int, a);
    unsigned int ub = __builtin_bit_cast(unsigned int, b);
    ua = (ua + 0x7fffu + ((ua >> 16) & 1u)) >> 16;   // RNE
    ub = (ub + 0x7fffu + ((ub >> 16) & 1u)) >> 16;
    return ua | (ub << 16);
}
__device__ inline unsigned short cvt1(float f) {
    unsigned int u = __builtin_bit_cast(unsigned int, f);
    return (unsigned short)((u + 0x7fffu + ((u >> 16) & 1u)) >> 16);
}

// ---------------- Stage 1: dense correlation on MFMA ------------------------
// Block: 256 thr = 4 waves. Tile: one (b, cm-pair), 16 y rows, all 128 x.
// Wave w owns x in [32w, 32w+32). Per x: 2 cm x 8 kc MFMAs (16x16x32 bf16).
// k = i*16 + j;  octet(kc,quad): i = 2kc + (quad>>1), j = (quad&1)*8 + e.
// A-octet = tm_pad[y0 + m + i][x + j0 .. +7]  (m = lane&15, contiguous in x).
__global__ __launch_bounds__(256) void corr_mfma(
    const float* __restrict__ tp, const float* __restrict__ tm,
    unsigned short* __restrict__ corrb)
{
    // [cm2][parity][31 rows][146 elem] bf16; pitch 73 dwords (odd-ish mod 32
    // -> A-frag bank spread), plane stride 2263 dwords.
    __shared__ __align__(16) unsigned short smA[2 * 2 * 31 * 146];  // 36208 B
    __shared__ __align__(16) unsigned short smT[4 * 16 * 40];       //  5120 B

    const int t    = threadIdx.x;
    const int wave = t >> 6, lane = t & 63;
    const int n    = lane & 15, quad = lane >> 4;   // n: A-row m / B-col ct
    const int qh   = quad >> 1, jq = quad & 1;

    const int y0   = (int)blockIdx.x << 4;          // 0..112
    const int pair = (int)blockIdx.y & 7;           // cm pair 0..7
    const int b    = (int)blockIdx.y >> 3;          // 0..7

    // --- stage tm tiles: rows y0..y0+30 (clamped), elems 0..143 (clamped),
    //     copy0[e]=tm[e], copy1[e]=tm[e+1] ---
    for (int cm2 = 0; cm2 < 2; ++cm2) {
        const float* src = tm + (((size_t)(b * 16 + pair * 2 + cm2)) << 14);
        for (int e = t; e < 31 * 144; e += 256) {
            int r = e / 144, c = e - r * 144;
            int gy = y0 + r; gy = gy > 127 ? 127 : gy;   // edge-replication pad
            int gx = c > 127 ? 127 : c;
            unsigned short h = cvt1(src[(gy << 7) + gx]);
            smA[((cm2 * 2 + 0) * 31 + r) * 146 + c] = h;
            if (c > 0)
                smA[((cm2 * 2 + 1) * 31 + r) * 146 + (c - 1)] = h;
        }
    }
    __syncthreads();

    // --- B-frags: templates, loaded once. bq[kc] lane(n=ct,quad):
    //     tp[b][n][i=2kc+qh][jq*8 .. +7] (8 consecutive fp32 -> bf16x8) ---
    bf16x8 bq[8];
    {
        const float* tpb = tp + (((size_t)(b * 16 + n)) << 8);
#pragma unroll
        for (int kc = 0; kc < 8; ++kc) {
            const float4* q = (const float4*)(tpb + (((2 * kc + qh) << 4) + (jq << 3)));
            float4 a = q[0], c4 = q[1];
            union { uint4 u; bf16x8 h; } cv;
            cv.u.x = pack_bf16x2(a.x, a.y);
            cv.u.y = pack_bf16x2(a.z, a.w);
            cv.u.z = pack_bf16x2(c4.x, c4.y);
            cv.u.w = pack_bf16x2(c4.z, c4.w);
            bq[kc] = cv.h;
        }
    }

    const unsigned* smAd = (const unsigned*)smA;
    unsigned short* smt  = smT + wave * 16 * 40;     // per-wave transpose buf
    const int x0w = wave << 5;

#pragma unroll 1
    for (int xi = 0; xi < 32; ++xi) {
        const int x   = x0w + xi;
        const int par = x & 1;
        const int xe  = x - par;
        // lane's base dword: copy plane par, row m+qh, elem xe+jq*8
        const int Dbase = par * 2263 + (n + qh) * 73 + ((xe + (jq << 3)) >> 1);

        f32x4 acc0 = {0.f, 0.f, 0.f, 0.f}, acc1 = {0.f, 0.f, 0.f, 0.f};
#pragma unroll
        for (int kc = 0; kc < 8; ++kc) {
            const int D0 = Dbase + kc * 146;          // +2 rows per kc
            const int D1 = D0 + 4526;                 // cm2=1 plane pair
            union { uint4 u; bf16x8 h; } a0, a1;
            a0.u.x = smAd[D0]; a0.u.y = smAd[D0 + 1];
            a0.u.z = smAd[D0 + 2]; a0.u.w = smAd[D0 + 3];
            a1.u.x = smAd[D1]; a1.u.y = smAd[D1 + 1];
            a1.u.z = smAd[D1 + 2]; a1.u.w = smAd[D1 + 3];
            acc0 = __builtin_amdgcn_mfma_f32_16x16x32_bf16(a0.h, bq[kc], acc0, 0, 0, 0);
            acc1 = __builtin_amdgcn_mfma_f32_16x16x32_bf16(a1.h, bq[kc], acc1, 0, 0, 0);
        }

        // Epilogue: D[row=quad*4+r][col=n] -> smt[pos][cm2*16+ct] (per-wave,
        // DS ops from one wave complete in order -> no barrier needed).
#pragma unroll
        for (int r = 0; r < 4; ++r) {
            smt[(quad * 4 + r) * 40 + n]      = cvt1(acc0[r]);
            smt[(quad * 4 + r) * 40 + 16 + n] = cvt1(acc1[r]);
        }
        // Read back 16 B/lane, store full 64-B lines: 32 channels per pos.
        const int pos  = lane >> 2, part = lane & 3;
        const uint4 vv = *(const uint4*)&smt[pos * 40 + part * 8];
        unsigned short* dst = corrb
            + (((size_t)(b * 16384 + (y0 + pos) * 128 + x)) << 8)
            + (pair << 5) + (part << 3);
        *(uint4*)dst = vv;
    }
}

// ---------------- W transform: [co][cin][3][3] fp32 -> Wb[kk][co][cpad] bf16 -
__global__ __launch_bounds__(256) void wt_kernel(
    const float* __restrict__ W, unsigned short* __restrict__ Wb,
    int c0g, int NCloc, int NCpad)
{
    int idx = (int)blockIdx.x * 256 + (int)threadIdx.x;
    int total = 9 * 64 * NCpad;
    if (idx >= total) return;
    int cloc = idx % NCpad;
    int rem  = idx / NCpad;
    int co   = rem % 64;
    int kk   = rem / 64;
    float v = 0.f;
    if (cloc < NCloc) v = W[(size_t)co * 2304 + (size_t)(c0g + cloc) * 9 + kk];
    Wb[idx] = cvt1(v);
}

// ---------------- Stage 2: 3x3 SAME merge conv on MFMA bf16 (unchanged) -----
__global__ __launch_bounds__(256) void merge_mfma(
    const unsigned short* __restrict__ corrb, const unsigned short* __restrict__ Wb,
    const float* __restrict__ bias, float* __restrict__ out,
    int NCloc, int NCpad, int first)
{
    __shared__ __align__(16) unsigned short sm[10 * 34 * 72];  // 48960 B

    const int t    = threadIdx.x;
    const int wave = t >> 6;
    const int lane = t & 63;
    const int n    = lane & 15;
    const int quad = lane >> 4;
    const int x0   = (int)blockIdx.x << 5;
    const int y0   = (int)blockIdx.y << 3;
    const int b    = (int)blockIdx.z;

    f32x4 acc[4][4];
#pragma unroll
    for (int a = 0; a < 4; ++a)
#pragma unroll
        for (int q = 0; q < 4; ++q) acc[a][q] = (f32x4){0.f, 0.f, 0.f, 0.f};

    const unsigned short* cb = corrb + (size_t)b * 16384 * NCloc;

#pragma unroll 1
    for (int c0 = 0; c0 < NCpad; c0 += 64) {
        __syncthreads();
        for (int e = t; e < 2720; e += 256) {
            int ci  = e & 7;
            int rem = e >> 3;
            int cc  = rem % 34;
            int r   = rem / 34;
            int gy = y0 - 1 + r;
            int gx = x0 - 1 + cc;
            int c  = c0 + (ci << 3);
            uint4 v = {0u, 0u, 0u, 0u};
            if ((unsigned)gy < 128u && (unsigned)gx < 128u && c < NCloc)
                v = *(const uint4*)(cb + ((size_t)((gy << 7) + gx)) * NCloc + c);
            *(uint4*)&sm[r * 2448 + cc * 72 + (ci << 3)] = v;
        }
        __syncthreads();

#pragma unroll 1
        for (int kk = 0; kk < 9; ++kk) {
            const int dy = kk / 3, dx = kk - 3 * (kk / 3);
#pragma unroll
            for (int kc = 0; kc < 2; ++kc) {
                bf16x8 af[4];
                const unsigned short* wp =
                    Wb + (size_t)kk * 64 * NCpad + (size_t)n * NCpad
                       + c0 + (kc << 5) + (quad << 3);
#pragma unroll
                for (int ct = 0; ct < 4; ++ct)
                    af[ct] = *(const bf16x8*)(wp + (size_t)(ct << 4) * NCpad);
#pragma unroll
                for (int nt = 0; nt < 4; ++nt) {
                    const int prow = 2 * wave + (nt >> 1) + dy;
                    const int pcol = ((nt & 1) << 4) + n + dx;
                    bf16x8 bf = *(const bf16x8*)&sm[prow * 2448 + pcol * 72
                                                    + (kc << 5) + (quad << 3)];
#pragma unroll
                    for (int ct = 0; ct < 4; ++ct)
                        acc[ct][nt] = __builtin_amdgcn_mfma_f32_16x16x32_bf16(
                            af[ct], bf, acc[ct][nt], 0, 0, 0);
                }
            }
        }
    }

#pragma unroll
    for (int ct = 0; ct < 4; ++ct) {
#pragma unroll
        for (int nt = 0; nt < 4; ++nt) {
            const int y   = y0 + 2 * wave + (nt >> 1);
            const int x   = x0 + ((nt & 1) << 4) + n;
            const int co0 = (ct << 4) + (quad << 2);
            float* op = out + (((size_t)((b << 6) + co0) << 7) + y) * 128 + x;
#pragma unroll
            for (int r = 0; r < 4; ++r) {
                float v = acc[ct][nt][r];
                float* pp = op + ((size_t)r << 14);
                if (first) v += bias[co0 + r];
                else       v += *pp;
                *pp = v;
            }
        }
    }
}

// ---------------- Fallback fp32 corr (only used if ws too small; S>1) -------
__global__ __launch_bounds__(256) void corr_kernel(
    const float* __restrict__ tp, const float* __restrict__ tm,
    unsigned short* __restrict__ corrb, int cm0, int CmC)
{
    __shared__ float sm_tm[47 * 84];
    __shared__ float sm_tp[256 * 8];

    const int t   = threadIdx.x;
    const int x0  = (blockIdx.x & 1) << 6;
    const int y0  = (blockIdx.x >> 1) << 5;
    const int cl  = (int)blockIdx.y % CmC;
    const int b   = (int)blockIdx.y / CmC;
    const int cm  = cm0 + cl;
    const int ct0 = (int)blockIdx.z << 3;
    const int NCloc = CmC << 4;

    const float* tm_base = tm + (((size_t)(b * 16 + cm)) << 14);
    for (int e = t; e < 47 * 84; e += 256) {
        int r = e / 84, c = e - r * 84;
        int gy = y0 + r; gy = gy > 127 ? 127 : gy;
        int gx = x0 + c; gx = gx > 127 ? 127 : gx;
        sm_tm[e] = tm_base[(gy << 7) + gx];
    }
    const float* tp_base = tp + (((size_t)(b * 16 + ct0)) << 8);
    for (int e = t; e < 2048; e += 256) {
        int ij = e >> 3, ctl = e & 7;
        sm_tp[e] = tp_base[(ctl << 8) + ij];
    }
    __syncthreads();

    const int ty  = t >> 3;
    const int txg = (t & 7) << 3;

    float acc[8][8];
#pragma unroll
    for (int c = 0; c < 8; ++c)
#pragma unroll
        for (int p = 0; p < 8; ++p) acc[c][p] = 0.f;

    const float* tmrow = sm_tm + ty * 84 + txg;
#pragma unroll 1
    for (int i = 0; i < 16; ++i) {
        float r[24];
        const float4* rp = (const float4*)(tmrow + i * 84);
#pragma unroll
        for (int q = 0; q < 6; ++q) {
            float4 v = rp[q];
            r[4*q] = v.x; r[4*q+1] = v.y; r[4*q+2] = v.z; r[4*q+3] = v.w;
        }
#pragma unroll
        for (int j = 0; j < 16; ++j) {
            const float4* w4 = (const float4*)(sm_tp + (((i << 4) + j) << 3));
            float4 wa = w4[0], wb = w4[1];
            float wv[8] = {wa.x, wa.y, wa.z, wa.w, wb.x, wb.y, wb.z, wb.w};
#pragma unroll
            for (int c = 0; c < 8; ++c)
#pragma unroll
                for (int p = 0; p < 8; ++p)
                    acc[c][p] += r[j + p] * wv[c];
        }
    }

    const int oy = y0 + ty, ox = x0 + txg;
    const size_t posbase = (size_t)b * 16384 + (oy << 7) + ox;
#pragma unroll
    for (int p = 0; p < 8; ++p) {
        uint4 v;
        v.x = pack_bf16x2(acc[0][p], acc[1][p]);
        v.y = pack_bf16x2(acc[2][p], acc[3][p]);
        v.z = pack_bf16x2(acc[4][p], acc[5][p]);
        v.w = pack_bf16x2(acc[6][p], acc[7][p]);
        *(uint4*)(corrb + (posbase + p) * NCloc + (cl << 4) + ct0) = v;
    }
}

extern "C" void kernel_launch(void* const* d_in, const int* in_sizes, int n_in,
                              void* d_out, int out_size, void* d_ws, size_t ws_size,
                              hipStream_t stream)
{
    const float* tp   = (const float*)d_in[0];
    const float* tm   = (const float*)d_in[1];
    const float* Wt   = (const float*)d_in[2];
    const float* bias = (const float*)d_in[3];
    float* out = (float*)d_out;

    int S = 1;
    for (;;) {
        int NCloc = 256 / S;
        int NCpad = (NCloc + 63) & ~63;
        size_t need = (size_t)8 * 16384 * NCloc * 2 + (size_t)9 * 64 * NCpad * 2 + 512;
        if (need <= ws_size || S == 16) break;
        S <<= 1;
    }
    const int CmC   = 16 / S;
    const int NCloc = CmC << 4;
    const int NCpad = (NCloc + 63) & ~63;

    unsigned short* corrb = (unsigned short*)d_ws;
    unsigned short* Wb    = corrb + (size_t)8 * 16384 * NCloc;

    for (int sc = 0; sc < S; ++sc) {
        if (S == 1) {
            corr_mfma<<<dim3(8, 64), dim3(256), 0, stream>>>(tp, tm, corrb);
        } else {
            dim3 g1(8, 8 * CmC, 2);
            corr_kernel<<<g1, dim3(256), 0, stream>>>(tp, tm, corrb, sc * CmC, CmC);
        }
        int wtotal = 9 * 64 * NCpad;
        wt_kernel<<<dim3((wtotal + 255) / 256), dim3(256), 0, stream>>>(
            Wt, Wb, sc * NCloc, NCloc, NCpad);
        dim3 g2(4, 16, 8);
        merge_mfma<<<g2, dim3(256), 0, stream>>>(corrb, Wb, bias, out,
                                                 NCloc, NCpad, sc == 0 ? 1 : 0);
    }
}

// Round 4
// 194.123 us; speedup vs baseline: 3.9737x; 1.0676x over previous
//
#include <hip/hip_runtime.h>
#include <hip/hip_bf16.h>

// ---------------------------------------------------------------------------
// DenseCorr2d_full — corr AND merge on MFMA bf16 (round 4).
//
// corr_mfma v2: tp as MFMA-A (m=ct), tm patches as MFMA-B (n=y-position).
//   D[row=quad*4+r = channel][col=n = y] -> each lane stores 4 consecutive
//   bf16 channels with one dwordx2 -> no LDS transpose, no serial epilogue.
//   Half-width x per block: LDS 20.3KB, grid 1024 = 4 blocks/CU.
// merge_mfma v2: register-prefetched slab staging + 1-chunk-ahead af frags.
// ws layout: corrb bf16 NHWC [8][128][128][256], then Wb bf16 [9][64][256].
// ---------------------------------------------------------------------------

typedef __attribute__((ext_vector_type(4))) float  f32x4;
typedef __attribute__((ext_vector_type(8))) short  bf16x8;

__device__ inline unsigned int pack_bf16x2(float a, float b) {
    unsigned int ua = __builtin_bit_cast(unsigned int, a);
    unsigned int ub = __builtin_bit_cast(unsigned int, b);
    ua = (ua + 0x7fffu + ((ua >> 16) & 1u)) >> 16;   // RNE
    ub = (ub + 0x7fffu + ((ub >> 16) & 1u)) >> 16;
    return ua | (ub << 16);
}
__device__ inline unsigned short cvt1(float f) {
    unsigned int u = __builtin_bit_cast(unsigned int, f);
    return (unsigned short)((u + 0x7fffu + ((u >> 16) & 1u)) >> 16);
}

// ---------------- Stage 1: dense correlation on MFMA ------------------------
// Block: 256 thr = 4 waves, 64-wide x range (xh selects half), 16 y rows,
// one (b, cm-pair). Wave w: x local [16w, 16w+16), 2 x per iteration.
// MFMA: A = tp (m=ct), B = tm patch (n = y). k = i*16+j;
// octet(kc,quad): i = 2kc + (quad>>1), j = (quad&1)*8 + e.
__global__ __launch_bounds__(256) void corr_mfma(
    const float* __restrict__ tp, const float* __restrict__ tm,
    unsigned short* __restrict__ corrb)
{
    // [cm2 2][parity 2][31 rows][82 shorts] ; pitch 41 dwords (odd -> banks
    // spread across the 16 n-lanes), plane stride 1271 dwords.
    __shared__ __align__(16) unsigned short smA[2 * 2 * 31 * 82];  // 20336 B

    const int t    = threadIdx.x;
    const int wave = t >> 6, lane = t & 63;
    const int n    = lane & 15, quad = lane >> 4;
    const int qh   = quad >> 1, jq = quad & 1;

    const int xh   = (int)blockIdx.x & 1;            // x half 0/1
    const int y0   = ((int)blockIdx.x >> 1) << 4;    // 0..112
    const int pair = (int)blockIdx.y & 7;            // cm pair
    const int b    = (int)blockIdx.y >> 3;
    const int xg0  = xh << 6;

    // --- stage tm: rows y0..y0+30 (clamped), cols xg0..xg0+79 (clamped);
    //     copy0[c] = tm[c], copy1[c-1] = tm[c]  (parity-shifted copy) ---
    for (int cm2 = 0; cm2 < 2; ++cm2) {
        const float* src = tm + (((size_t)(b * 16 + pair * 2 + cm2)) << 14);
        for (int e = t; e < 31 * 80; e += 256) {
            int r = e / 80, c = e - r * 80;
            int gy = y0 + r;  gy = gy > 127 ? 127 : gy;   // edge-replication
            int gx = xg0 + c; gx = gx > 127 ? 127 : gx;
            unsigned short h = cvt1(src[(gy << 7) + gx]);
            smA[((cm2 * 2 + 0) * 31 + r) * 82 + c] = h;
            if (c > 0)
                smA[((cm2 * 2 + 1) * 31 + r) * 82 + (c - 1)] = h;
        }
    }
    __syncthreads();

    // --- tp frags (MFMA-A operand, m = ct = n): tp[b][n][i=2kc+qh][jq*8..+7]
    bf16x8 bq[8];
    {
        const float* tpb = tp + (((size_t)(b * 16 + n)) << 8);
#pragma unroll
        for (int kc = 0; kc < 8; ++kc) {
            const float4* q = (const float4*)(tpb + (((2 * kc + qh) << 4) + (jq << 3)));
            float4 a = q[0], c4 = q[1];
            union { uint4 u; bf16x8 h; } cv;
            cv.u.x = pack_bf16x2(a.x, a.y);
            cv.u.y = pack_bf16x2(a.z, a.w);
            cv.u.z = pack_bf16x2(c4.x, c4.y);
            cv.u.w = pack_bf16x2(c4.z, c4.w);
            bq[kc] = cv.h;
        }
    }

    const unsigned* smAd = (const unsigned*)smA;
    const int PITCH = 41, PLANE = 31 * 41;           // dwords

#pragma unroll 1
    for (int it = 0; it < 8; ++it) {
        const int lxa  = (wave << 4) + (it << 1);    // even local x
        // lane base dword: row n+qh, elem lxa + jq*8 (even -> exact)
        const int D00  = (n + qh) * PITCH + ((lxa + (jq << 3)) >> 1);

        f32x4 acc[4];                                // [cm2*2 + xparity]
#pragma unroll
        for (int q = 0; q < 4; ++q) acc[q] = (f32x4){0.f, 0.f, 0.f, 0.f};

#pragma unroll
        for (int kc = 0; kc < 8; ++kc) {
            const int dof = D00 + kc * 82;           // +2 rows per kc
#pragma unroll
            for (int ch = 0; ch < 4; ++ch) {         // ch = cm2*2 + par
                const int d = dof + ch * PLANE;      // plane order: cm2,par
                union { uint4 u; bf16x8 h; } fr;
                fr.u.x = smAd[d];     fr.u.y = smAd[d + 1];
                fr.u.z = smAd[d + 2]; fr.u.w = smAd[d + 3];
                // plane ch: cm2 = ch>>1, par = ch&1 -> x = lxa + (ch&1)
                const int ai = ((ch & 1) << 1) | (ch >> 1);  // acc idx: par*2+cm2
                acc[ai] = __builtin_amdgcn_mfma_f32_16x16x32_bf16(
                    bq[kc], fr.h, acc[ai], 0, 0, 0);
            }
        }

        // Epilogue: D[row=quad*4+r = ch][col=n = y]; 4 consecutive channels
        // per lane -> one 8B store per (x, cm2).
        const int y = y0 + n;
#pragma unroll
        for (int ai = 0; ai < 4; ++ai) {
            const int par = ai >> 1, cm2 = ai & 1;
            const int x   = xg0 + lxa + par;
            uint2 v;
            v.x = pack_bf16x2(acc[ai][0], acc[ai][1]);
            v.y = pack_bf16x2(acc[ai][2], acc[ai][3]);
            unsigned short* dst = corrb
                + (((size_t)(b * 16384 + (y << 7) + x)) << 8)
                + (pair << 5) + (cm2 << 4) + (quad << 2);
            *(uint2*)dst = v;
        }
    }
}

// ---------------- W transform: [co][cin][3][3] fp32 -> Wb[kk][co][256] bf16 -
__global__ __launch_bounds__(256) void wt_kernel(
    const float* __restrict__ W, unsigned short* __restrict__ Wb)
{
    int idx = (int)blockIdx.x * 256 + (int)threadIdx.x;   // < 9*64*256
    int c  = idx & 255;
    int rem = idx >> 8;
    int co = rem % 64;
    int kk = rem / 64;
    Wb[idx] = cvt1(W[(size_t)co * 2304 + (size_t)c * 9 + kk]);
}

// ---------------- Stage 2: 3x3 SAME merge conv on MFMA bf16 -----------------
// Tile 64co x (8y x 32x); K-loop over 4 slabs of 64 ch with register
// prefetch of the next slab during compute, af frags prefetched 1 chunk ahead.
__global__ __launch_bounds__(256) void merge_mfma(
    const unsigned short* __restrict__ corrb, const unsigned short* __restrict__ Wb,
    const float* __restrict__ bias, float* __restrict__ out)
{
    __shared__ __align__(16) unsigned short sm[10 * 34 * 72];  // 48960 B

    const int t    = threadIdx.x;
    const int wave = t >> 6, lane = t & 63;
    const int n    = lane & 15, quad = lane >> 4;
    const int x0   = (int)blockIdx.x << 5;
    const int y0   = (int)blockIdx.y << 3;
    const int b    = (int)blockIdx.z;

    f32x4 acc[4][4];
#pragma unroll
    for (int a = 0; a < 4; ++a)
#pragma unroll
        for (int q = 0; q < 4; ++q) acc[a][q] = (f32x4){0.f, 0.f, 0.f, 0.f};

    const unsigned short* cb = corrb + ((size_t)b << 22);   // b * 16384*256

    // Slab staging: 2720 uint4 elems; each thread handles k = 0..10.
    uint4 v[11];

    // helper expressed inline twice (loads / writes) to keep deps decoupled
#define SLAB_LOAD(C0)                                                        \
    {                                                                        \
        _Pragma("unroll")                                                    \
        for (int k = 0; k < 11; ++k) {                                       \
            int e = t + (k << 8);                                            \
            int ci = e & 7, rem = e >> 3;                                    \
            int cc = rem % 34, r = rem / 34;                                 \
            int gy = y0 - 1 + r, gx = x0 - 1 + cc;                           \
            uint4 vv = {0u, 0u, 0u, 0u};                                     \
            if (e < 2720 && (unsigned)gy < 128u && (unsigned)gx < 128u)      \
                vv = *(const uint4*)(cb + (((size_t)((gy << 7) + gx)) << 8)  \
                                        + (C0) + (ci << 3));                 \
            v[k] = vv;                                                       \
        }                                                                    \
    }
#define SLAB_WRITE()                                                         \
    {                                                                        \
        _Pragma("unroll")                                                    \
        for (int k = 0; k < 11; ++k) {                                       \
            int e = t + (k << 8);                                            \
            int ci = e & 7, rem = e >> 3;                                    \
            int cc = rem % 34, r = rem / 34;                                 \
            if (e < 2720)                                                    \
                *(uint4*)&sm[r * 2448 + cc * 72 + (ci << 3)] = v[k];         \
        }                                                                    \
    }

    SLAB_LOAD(0)
    SLAB_WRITE()
    __syncthreads();

#pragma unroll 1
    for (int c0 = 0; c0 < 256; c0 += 64) {
        if (c0 < 192) SLAB_LOAD(c0 + 64)            // prefetch next slab

        // af chunk address: Wb[kk][co=ct*16+n][c0 + kc*32 + quad*8]
        const unsigned short* wpb = Wb + (size_t)n * 256 + c0 + (quad << 3);
        bf16x8 afc[4];
        {
#pragma unroll
            for (int ct = 0; ct < 4; ++ct)
                afc[ct] = *(const bf16x8*)(wpb + (size_t)ct * 4096);
        }
#pragma unroll 1
        for (int idx = 0; idx < 18; ++idx) {
            const int nidx = idx < 17 ? idx + 1 : 17;
            const int nkk = nidx >> 1, nkc = nidx & 1;
            bf16x8 afn[4];
#pragma unroll
            for (int ct = 0; ct < 4; ++ct)
                afn[ct] = *(const bf16x8*)(wpb + (size_t)nkk * 16384
                                               + (nkc << 5) + (size_t)ct * 4096);
            const int kk = idx >> 1, kc = idx & 1;
            const int dy = kk / 3, dx = kk - 3 * dy;
#pragma unroll
            for (int nt = 0; nt < 4; ++nt) {
                const int prow = 2 * wave + (nt >> 1) + dy;
                const int pcol = ((nt & 1) << 4) + n + dx;
                bf16x8 bf = *(const bf16x8*)&sm[prow * 2448 + pcol * 72
                                                + (kc << 5) + (quad << 3)];
#pragma unroll
                for (int ct = 0; ct < 4; ++ct)
                    acc[ct][nt] = __builtin_amdgcn_mfma_f32_16x16x32_bf16(
                        afc[ct], bf, acc[ct][nt], 0, 0, 0);
            }
#pragma unroll
            for (int ct = 0; ct < 4; ++ct) afc[ct] = afn[ct];
        }

        __syncthreads();                             // all waves done with sm
        if (c0 < 192) SLAB_WRITE()
        __syncthreads();
    }

    // Epilogue: D[row=quad*4+r = co][col=n], + bias, fp32 out
#pragma unroll
    for (int ct = 0; ct < 4; ++ct) {
#pragma unroll
        for (int nt = 0; nt < 4; ++nt) {
            const int y   = y0 + 2 * wave + (nt >> 1);
            const int x   = x0 + ((nt & 1) << 4) + n;
            const int co0 = (ct << 4) + (quad << 2);
            float* op = out + (((size_t)((b << 6) + co0) << 7) + y) * 128 + x;
#pragma unroll
            for (int r = 0; r < 4; ++r)
                op[(size_t)r << 14] = acc[ct][nt][r] + bias[co0 + r];
        }
    }
#undef SLAB_LOAD
#undef SLAB_WRITE
}

extern "C" void kernel_launch(void* const* d_in, const int* in_sizes, int n_in,
                              void* d_out, int out_size, void* d_ws, size_t ws_size,
                              hipStream_t stream)
{
    const float* tp   = (const float*)d_in[0];   // template [8,16,16,16]
    const float* tm   = (const float*)d_in[1];   // tomatch  [8,16,128,128]
    const float* Wt   = (const float*)d_in[2];   // W        [64,256,3,3]
    const float* bias = (const float*)d_in[3];   // b        [64]
    float* out = (float*)d_out;                  // [8,64,128,128] fp32

    unsigned short* corrb = (unsigned short*)d_ws;              // 67.1 MB
    unsigned short* Wb    = corrb + (size_t)8 * 16384 * 256;    // 294 KB

    corr_mfma<<<dim3(16, 64), dim3(256), 0, stream>>>(tp, tm, corrb);
    wt_kernel<<<dim3(576), dim3(256), 0, stream>>>(Wt, Wb);
    merge_mfma<<<dim3(4, 16, 8), dim3(256), 0, stream>>>(corrb, Wb, bias, out);
}